// Round 6
// baseline (294.725 us; speedup 1.0000x reference)
//
#include <hip/hip_runtime.h>
#include <math.h>

#define BB 2
#define HH 512
#define WWD 512
#define HWW (HH*WWD)
#define NCH_OUT 21

// ---------- small dense helpers (row-major, constant-indexed -> registers) ----------

__device__ __forceinline__ void inv4(const float a[16], float b[16]) {
    float s0 = a[0]*a[5] - a[4]*a[1];
    float s1 = a[0]*a[6] - a[4]*a[2];
    float s2 = a[0]*a[7] - a[4]*a[3];
    float s3 = a[1]*a[6] - a[5]*a[2];
    float s4 = a[1]*a[7] - a[5]*a[3];
    float s5 = a[2]*a[7] - a[6]*a[3];
    float c5 = a[10]*a[15] - a[14]*a[11];
    float c4 = a[9]*a[15]  - a[13]*a[11];
    float c3 = a[9]*a[14]  - a[13]*a[10];
    float c2 = a[8]*a[15]  - a[12]*a[11];
    float c1 = a[8]*a[14]  - a[12]*a[10];
    float c0 = a[8]*a[13]  - a[12]*a[9];
    float det = s0*c5 - s1*c4 + s2*c3 + s3*c2 - s4*c1 + s5*c0;
    float id = 1.0f / det;
    b[0]  = ( a[5]*c5  - a[6]*c4  + a[7]*c3 ) * id;
    b[1]  = (-a[1]*c5  + a[2]*c4  - a[3]*c3 ) * id;
    b[2]  = ( a[13]*s5 - a[14]*s4 + a[15]*s3) * id;
    b[3]  = (-a[9]*s5  + a[10]*s4 - a[11]*s3) * id;
    b[4]  = (-a[4]*c5  + a[6]*c2  - a[7]*c1 ) * id;
    b[5]  = ( a[0]*c5  - a[2]*c2  + a[3]*c1 ) * id;
    b[6]  = (-a[12]*s5 + a[14]*s2 - a[15]*s1) * id;
    b[7]  = ( a[8]*s5  - a[10]*s2 + a[11]*s1) * id;
    b[8]  = ( a[4]*c4  - a[5]*c2  + a[7]*c0 ) * id;
    b[9]  = (-a[0]*c4  + a[1]*c2  - a[3]*c0 ) * id;
    b[10] = ( a[12]*s4 - a[13]*s2 + a[15]*s0) * id;
    b[11] = (-a[8]*s4  + a[9]*s2  - a[11]*s0) * id;
    b[12] = (-a[4]*c3  + a[5]*c1  - a[6]*c0 ) * id;
    b[13] = ( a[0]*c3  - a[1]*c1  + a[2]*c0 ) * id;
    b[14] = (-a[12]*s3 + a[13]*s1 - a[14]*s0) * id;
    b[15] = ( a[8]*s3  - a[9]*s1  + a[10]*s0) * id;
}

__device__ __forceinline__ void mm4(const float a[16], const float b[16], float c[16]) {
    #pragma unroll
    for (int i = 0; i < 4; i++)
        #pragma unroll
        for (int j = 0; j < 4; j++)
            c[i*4+j] = a[i*4]*b[j] + a[i*4+1]*b[4+j] + a[i*4+2]*b[8+j] + a[i*4+3]*b[12+j];
}

__device__ __forceinline__ void mm3(const float a[9], const float b[9], float c[9]) {
    #pragma unroll
    for (int i = 0; i < 3; i++)
        #pragma unroll
        for (int j = 0; j < 3; j++)
            c[i*3+j] = a[i*3]*b[j] + a[i*3+1]*b[3+j] + a[i*3+2]*b[6+j];
}

__device__ __forceinline__ float det3(const float g[9]) {
    return g[0]*(g[4]*g[8]-g[5]*g[7])
         - g[1]*(g[3]*g[8]-g[5]*g[6])
         + g[2]*(g[3]*g[7]-g[4]*g[6]);
}

__device__ __forceinline__ void inv3(const float g[9], float o[9]) {
    float c00 = g[4]*g[8] - g[5]*g[7];
    float c01 = g[5]*g[6] - g[3]*g[8];
    float c02 = g[3]*g[7] - g[4]*g[6];
    float det = g[0]*c00 + g[1]*c01 + g[2]*c02;
    float id = 1.0f / det;
    o[0] = c00 * id;
    o[1] = (g[2]*g[7] - g[1]*g[8]) * id;
    o[2] = (g[1]*g[5] - g[2]*g[4]) * id;
    o[3] = c01 * id;
    o[4] = (g[0]*g[8] - g[2]*g[6]) * id;
    o[5] = (g[2]*g[3] - g[0]*g[5]) * id;
    o[6] = c02 * id;
    o[7] = (g[1]*g[6] - g[0]*g[7]) * id;
    o[8] = (g[0]*g[4] - g[1]*g[3]) * id;
}

// ---------- per-pixel Mueller decomposition (fp32 in/out; R2-proven math) ----------

__device__ __forceinline__ void mm_main_body(
    int idx,
    const float* __restrict__ x,
    float* __restrict__ out,
    float2* __restrict__ cs_sn)
{
    int b = idx >> 18;            // HWW = 2^18
    int p = idx & (HWW - 1);
    const float* xb = x + (size_t)b * 48 * HWW + p;

    float Im[16], Am[16], Wm[16];
    #pragma unroll
    for (int k = 0; k < 16; k++) Im[k] = xb[(size_t)k * HWW];
    #pragma unroll
    for (int k = 0; k < 16; k++) Am[k] = xb[(size_t)(16 + k) * HWW];
    #pragma unroll
    for (int k = 0; k < 16; k++) Wm[k] = xb[(size_t)(32 + k) * HWW];

    float inten = 0.0f;
    #pragma unroll
    for (int k = 0; k < 16; k++) inten += Im[k];
    inten *= (1.0f / 16.0f);

    float iA[16], iW[16], T4[16], M[16];
    inv4(Am, iA);
    inv4(Wm, iW);
    mm4(iA, Im, T4);
    mm4(T4, iW, M);

    float* ob = out + (size_t)b * NCH_OUT * HWW + p;
    ob[0] = inten;
    #pragma unroll
    for (int k = 0; k < 16; k++) ob[(size_t)(1 + k) * HWW] = M[k];

    // ---- charpoly realizability mask via coherency matrix H ----
    float c00r[4], c11r[4], c01r[4], c01i[4];
    #pragma unroll
    for (int i = 0; i < 4; i++) {
        c00r[i] = M[4*i+0] + M[4*i+1];
        c11r[i] = M[4*i+0] - M[4*i+1];
        c01r[i] = M[4*i+2];
        c01i[i] = M[4*i+3];
    }
    float Hr[4][4], Hi[4][4];
    Hr[0][0] = 0.25f*(c00r[0]+c00r[1]); Hi[0][0] = 0.0f;
    Hr[0][1] = 0.25f*(c01r[0]+c01r[1]); Hi[0][1] = 0.25f*(c01i[0]+c01i[1]);
    Hr[1][0] = Hr[0][1];                Hi[1][0] = -Hi[0][1];
    Hr[1][1] = 0.25f*(c11r[0]+c11r[1]); Hi[1][1] = 0.0f;
    Hr[0][2] = 0.25f* c00r[2];               Hi[0][2] = -0.25f*c00r[3];
    Hr[0][3] = 0.25f*(c01r[2]+c01i[3]);      Hi[0][3] = 0.25f*(c01i[2]-c01r[3]);
    Hr[1][2] = 0.25f*(c01r[2]-c01i[3]);      Hi[1][2] = 0.25f*(-c01i[2]-c01r[3]);
    Hr[1][3] = 0.25f* c11r[2];               Hi[1][3] = -0.25f*c11r[3];
    Hr[2][0] = 0.25f* c00r[2];               Hi[2][0] = 0.25f*c00r[3];
    Hr[2][1] = 0.25f*(c01r[2]-c01i[3]);      Hi[2][1] = 0.25f*(c01i[2]+c01r[3]);
    Hr[3][0] = 0.25f*(c01r[2]+c01i[3]);      Hi[3][0] = 0.25f*(-c01i[2]+c01r[3]);
    Hr[3][1] = 0.25f* c11r[2];               Hi[3][1] = 0.25f*c11r[3];
    Hr[2][2] = 0.25f*(c00r[0]-c00r[1]); Hi[2][2] = 0.0f;
    Hr[2][3] = 0.25f*(c01r[0]-c01r[1]); Hi[2][3] = 0.25f*(c01i[0]-c01i[1]);
    Hr[3][2] = Hr[2][3];                Hi[3][2] = -Hi[2][3];
    Hr[3][3] = 0.25f*(c11r[0]-c11r[1]); Hi[3][3] = 0.0f;

    float p1 = Hr[0][0]+Hr[1][1]+Hr[2][2]+Hr[3][3];
    float p2 = 0.0f, p3 = 0.0f, p4 = 0.0f;
    #pragma unroll
    for (int i = 0; i < 4; i++) {
        #pragma unroll
        for (int j = 0; j < 4; j++) {
            float h2r = 0.0f, h2i = 0.0f;
            #pragma unroll
            for (int k = 0; k < 4; k++) {
                h2r += Hr[i][k]*Hr[k][j] - Hi[i][k]*Hi[k][j];
                h2i += Hr[i][k]*Hi[k][j] + Hi[i][k]*Hr[k][j];
            }
            if (i == j) p2 += h2r;
            p3 += h2r*Hr[i][j] + h2i*Hi[i][j];
            p4 += h2r*h2r + h2i*h2i;
        }
    }
    float cc1 = p1;
    float cc2 = (cc1*p1 - p2) * 0.5f;
    float cc3 = (cc2*p1 - cc1*p2 + p3) * (1.0f/3.0f);
    float cc4 = (cc3*p1 - cc2*p2 + cc1*p3 - p4) * 0.25f;
    const float tol = -1e-5f;
    bool v = (cc1 > tol) && (cc2 > tol) && (cc3 > tol) && (cc4 > tol);

    // ---- diattenuator removal ----
    float im00 = 1.0f / (M[0] + 1e-6f);
    float Mn[16];
    #pragma unroll
    for (int k = 0; k < 16; k++) Mn[k] = M[k] * im00;
    float D0 = Mn[1], D1 = Mn[2], D2 = Mn[3];
    float d = sqrtf(D0*D0 + D1*D1 + D2*D2 + 1e-12f);
    float dcl = fminf(fmaxf(d, 0.0f), 0.9999f);
    float sq = sqrtf(1.0f - dcl*dcl);
    float idn = 1.0f / (d + 1e-9f);
    float Dn0 = D0*idn, Dn1 = D1*idn, Dn2 = D2*idn;
    float osq = 1.0f - sq;
    float MD[16];
    MD[0] = 1.0f; MD[1] = D0; MD[2] = D1; MD[3] = D2;
    MD[4] = D0;  MD[8] = D1; MD[12] = D2;
    MD[5]  = sq + osq*Dn0*Dn0; MD[6]  = osq*Dn0*Dn1;      MD[7]  = osq*Dn0*Dn2;
    MD[9]  = osq*Dn1*Dn0;      MD[10] = sq + osq*Dn1*Dn1; MD[11] = osq*Dn1*Dn2;
    MD[13] = osq*Dn2*Dn0;      MD[14] = osq*Dn2*Dn1;      MD[15] = sq + osq*Dn2*Dn2;
    float iMD[16]; inv4(MD, iMD);
    float Mp[16]; mm4(Mn, iMD, Mp);
    float mp[9] = {Mp[5],Mp[6],Mp[7], Mp[9],Mp[10],Mp[11], Mp[13],Mp[14],Mp[15]};

    float G[9];
    G[0] = mp[0]*mp[0]+mp[1]*mp[1]+mp[2]*mp[2];
    G[1] = mp[0]*mp[3]+mp[1]*mp[4]+mp[2]*mp[5];
    G[2] = mp[0]*mp[6]+mp[1]*mp[7]+mp[2]*mp[8];
    G[3] = G[1];
    G[4] = mp[3]*mp[3]+mp[4]*mp[4]+mp[5]*mp[5];
    G[5] = mp[3]*mp[6]+mp[4]*mp[7]+mp[5]*mp[8];
    G[6] = G[2]; G[7] = G[5];
    G[8] = mp[6]*mp[6]+mp[7]*mp[7]+mp[8]*mp[8];

    // ---- eigvals of symmetric 3x3 (trig formula) ----
    float qq = (G[0]+G[4]+G[8]) * (1.0f/3.0f);
    float Gq[9];
    #pragma unroll
    for (int k = 0; k < 9; k++) Gq[k] = G[k];
    Gq[0] -= qq; Gq[4] -= qq; Gq[8] -= qq;
    float ssum = 0.0f;
    #pragma unroll
    for (int k = 0; k < 9; k++) ssum += Gq[k]*Gq[k];
    float pp = sqrtf(ssum * (1.0f/6.0f) + 1e-20f);
    float rr = det3(Gq) / (2.0f * pp*pp*pp);
    rr = fminf(fmaxf(rr, -1.0f + 1e-6f), 1.0f - 1e-6f);
    float phi = acosf(rr) * (1.0f/3.0f);
    float l1 = qq + 2.0f*pp*cosf(phi);
    float l3 = qq + 2.0f*pp*cosf(phi + 2.0943951023931953f);
    float l2 = 3.0f*qq - l1 - l3;

    float s1v = sqrtf(fmaxf(l1, 1e-12f));
    float s2v = sqrtf(fmaxf(l2, 1e-12f));
    float s3v = sqrtf(fmaxf(l3, 1e-12f));
    float e1 = s1v + s2v + s3v;
    float e2 = s1v*s2v + s2v*s3v + s3v*s1v;
    float e3 = s1v*s2v*s3v;
    float sgn = (det3(mp) >= 0.0f) ? 1.0f : -1.0f;

    float LHS[9], RHS[9];
    #pragma unroll
    for (int k = 0; k < 9; k++) { LHS[k] = G[k]; RHS[k] = e1*G[k]; }
    float e2p = e2 + 1e-9f;
    LHS[0] += e2p; LHS[4] += e2p; LHS[8] += e2p;
    RHS[0] += e3;  RHS[4] += e3;  RHS[8] += e3;
    float iL[9]; inv3(LHS, iL);
    float mDel[9]; mm3(iL, RHS, mDel);
    #pragma unroll
    for (int k = 0; k < 9; k++) mDel[k] *= sgn;
    float iDel[9]; inv3(mDel, iDel);
    float mR[9]; mm3(iDel, mp, mR);

    float t1 = mR[0] + mR[4];
    float t2 = mR[3] - mR[1];
    float arg = sqrtf(t1*t1 + t2*t2 + 1e-12f) - 1.0f;
    arg = fminf(fmaxf(arg, -1.0f + 1e-6f), 1.0f - 1e-6f);
    const float RAD2DEG = 57.29577951308232f;
    float linr = acosf(arg) * RAD2DEG;
    float a1 = mR[5] - mR[7];
    float a2 = mR[6] - mR[2];
    bool safe = (a1*a1 + a2*a2) > 1e-12f;
    float azi = 0.5f * RAD2DEG * atan2f(safe ? a2 : 0.0f, safe ? a1 : 1.0f);
    azi = fmodf(azi, 180.0f);
    if (azi < 0.0f) azi += 180.0f;
    float totp = 1.0f - (fabsf(mDel[0])+fabsf(mDel[4])+fabsf(mDel[8])) * (1.0f/3.0f);
    if (!v) { linr = 0.0f; totp = 0.0f; azi = 0.0f; }

    ob[(size_t)17 * HWW] = linr;
    ob[(size_t)18 * HWW] = totp;
    ob[(size_t)19 * HWW] = azi;

    if (cs_sn) {
        float ang = azi * 0.03490658503988659f; // 2 * radians(azi)
        cs_sn[idx] = make_float2(cosf(ang), sinf(ang));
    }
}

// Variant A: forced 8 waves/EU (caps VGPR at 64, may spill). Variant B: default.
__global__ __launch_bounds__(256, 8) void mm_main_w8(
    const float* __restrict__ x, float* __restrict__ out,
    float2* __restrict__ cs_sn, int pix_base, int pix_count)
{
    int gid = blockIdx.x * 256 + threadIdx.x;
    if (gid >= pix_count) return;
    mm_main_body(pix_base + gid, x, out, cs_sn);
}

__global__ __launch_bounds__(256) void mm_main_def(
    const float* __restrict__ x, float* __restrict__ out,
    float2* __restrict__ cs_sn, int pix_base, int pix_count)
{
    int gid = blockIdx.x * 256 + threadIdx.x;
    if (gid >= pix_count) return;
    mm_main_body(pix_base + gid, x, out, cs_sn);
}

// ---------- LDS-tiled separable 8x8 reflect box filter -> circular std ----------

__global__ __launch_bounds__(256) void mm_std_ws(
    const float2* __restrict__ cs_sn, float* __restrict__ out)
{
    __shared__ float2 tile[23][24];  // rows y0-4..y0+18, cols x0-4..x0+18
    __shared__ float2 Hs[23][17];    // horizontal 8-sums
    int tid = threadIdx.x;
    int x0 = blockIdx.x * 16, y0 = blockIdx.y * 16, b = blockIdx.z;
    const float2* src = cs_sn + (size_t)b * HWW;

    for (int e = tid; e < 529; e += 256) {   // 23x23 halo tile
        int ty = e / 23, tx = e - ty * 23;
        int gy = y0 - 4 + ty; gy = gy < 0 ? -gy : (gy >= HH ? 2*HH - 2 - gy : gy);
        int gx = x0 - 4 + tx; gx = gx < 0 ? -gx : (gx >= WWD ? 2*WWD - 2 - gx : gx);
        tile[ty][tx] = src[gy * WWD + gx];
    }
    __syncthreads();

    for (int e = tid; e < 368; e += 256) {   // 23 rows x 16 out-cols
        int r = e >> 4, c = e & 15;
        float2 a = tile[r][c];
        float sc = a.x, ss = a.y;
        #pragma unroll
        for (int k = 1; k < 8; k++) { float2 t = tile[r][c + k]; sc += t.x; ss += t.y; }
        Hs[r][c] = make_float2(sc, ss);
    }
    __syncthreads();

    int tx = tid & 15, ty = tid >> 4;
    float2 a = Hs[ty][tx];
    float Cs = a.x, Ss = a.y;
    #pragma unroll
    for (int k = 1; k < 8; k++) { float2 t = Hs[ty + k][tx]; Cs += t.x; Ss += t.y; }
    Cs *= (1.0f/64.0f);
    Ss *= (1.0f/64.0f);
    float R = sqrtf(Cs*Cs + Ss*Ss + 1e-12f);
    R = fminf(fmaxf(R, 1e-6f), 1.0f - 1e-7f);
    float stdv = 57.29577951308232f * 0.5f * sqrtf(-2.0f * logf(R));
    out[((size_t)(b * NCH_OUT + 20)) * HWW + (size_t)(y0 + ty) * WWD + (x0 + tx)] = stdv;
}

// Fallback (ws too small): recompute cos/sin from azi output channel, naive 64-tap.
__global__ __launch_bounds__(256) void mm_std_nws(float* __restrict__ out)
{
    int x = blockIdx.x * 16 + (threadIdx.x & 15);
    int y = blockIdx.y * 16 + (threadIdx.x >> 4);
    int b = blockIdx.z;
    const float* azi_ch = out + ((size_t)(b * NCH_OUT + 19)) * HWW;
    float Cs = 0.0f, Ss = 0.0f;
    #pragma unroll
    for (int ky = 0; ky < 8; ky++) {
        int yy = y - 4 + ky;
        yy = (yy < 0) ? -yy : ((yy >= HH) ? (2*HH - 2 - yy) : yy);
        int rowoff = yy * WWD;
        #pragma unroll
        for (int kx = 0; kx < 8; kx++) {
            int xx = x - 4 + kx;
            xx = (xx < 0) ? -xx : ((xx >= WWD) ? (2*WWD - 2 - xx) : xx);
            float azi = azi_ch[rowoff + xx];
            float ang = azi * 0.03490658503988659f;
            Cs += cosf(ang);
            Ss += sinf(ang);
        }
    }
    Cs *= (1.0f/64.0f);
    Ss *= (1.0f/64.0f);
    float R = sqrtf(Cs*Cs + Ss*Ss + 1e-12f);
    R = fminf(fmaxf(R, 1e-6f), 1.0f - 1e-7f);
    float stdv = 57.29577951308232f * 0.5f * sqrtf(-2.0f * logf(R));
    out[((size_t)(b * NCH_OUT + 20)) * HWW + (size_t)y * WWD + x] = stdv;
}

extern "C" void kernel_launch(void* const* d_in, const int* in_sizes, int n_in,
                              void* d_out, int out_size, void* d_ws, size_t ws_size,
                              hipStream_t stream) {
    const float* x = (const float*)d_in[0];
    float* out = (float*)d_out;
    const size_t ws_needed = sizeof(float2) * (size_t)BB * HWW;  // 4 MiB
    bool ws_ok = ws_size >= ws_needed;
    float2* cs_sn = ws_ok ? (float2*)d_ws : nullptr;

    // A/B within one bench: first half via forced-occupancy variant, second half default.
    const int half = BB * HWW / 2;
    dim3 gh((half + 255) / 256);
    mm_main_w8 <<<gh, 256, 0, stream>>>(x, out, cs_sn, 0, half);
    mm_main_def<<<gh, 256, 0, stream>>>(x, out, cs_sn, half, half);

    dim3 g2(WWD / 16, HH / 16, BB);
    if (ws_ok) {
        mm_std_ws<<<g2, 256, 0, stream>>>(cs_sn, out);
    } else {
        mm_std_nws<<<g2, 256, 0, stream>>>(out);
    }
}

// Round 7
// 169.270 us; speedup vs baseline: 1.7412x; 1.7412x over previous
//
#include <hip/hip_runtime.h>
#include <math.h>

#define BB 2
#define HH 512
#define WWD 512
#define HWW (HH*WWD)
#define NCH_OUT 21

// ---------- small dense helpers (row-major, constant-indexed -> registers) ----------

__device__ __forceinline__ void inv4(const float a[16], float b[16]) {
    float s0 = a[0]*a[5] - a[4]*a[1];
    float s1 = a[0]*a[6] - a[4]*a[2];
    float s2 = a[0]*a[7] - a[4]*a[3];
    float s3 = a[1]*a[6] - a[5]*a[2];
    float s4 = a[1]*a[7] - a[5]*a[3];
    float s5 = a[2]*a[7] - a[6]*a[3];
    float c5 = a[10]*a[15] - a[14]*a[11];
    float c4 = a[9]*a[15]  - a[13]*a[11];
    float c3 = a[9]*a[14]  - a[13]*a[10];
    float c2 = a[8]*a[15]  - a[12]*a[11];
    float c1 = a[8]*a[14]  - a[12]*a[10];
    float c0 = a[8]*a[13]  - a[12]*a[9];
    float det = s0*c5 - s1*c4 + s2*c3 + s3*c2 - s4*c1 + s5*c0;
    float id = 1.0f / det;
    b[0]  = ( a[5]*c5  - a[6]*c4  + a[7]*c3 ) * id;
    b[1]  = (-a[1]*c5  + a[2]*c4  - a[3]*c3 ) * id;
    b[2]  = ( a[13]*s5 - a[14]*s4 + a[15]*s3) * id;
    b[3]  = (-a[9]*s5  + a[10]*s4 - a[11]*s3) * id;
    b[4]  = (-a[4]*c5  + a[6]*c2  - a[7]*c1 ) * id;
    b[5]  = ( a[0]*c5  - a[2]*c2  + a[3]*c1 ) * id;
    b[6]  = (-a[12]*s5 + a[14]*s2 - a[15]*s1) * id;
    b[7]  = ( a[8]*s5  - a[10]*s2 + a[11]*s1) * id;
    b[8]  = ( a[4]*c4  - a[5]*c2  + a[7]*c0 ) * id;
    b[9]  = (-a[0]*c4  + a[1]*c2  - a[3]*c0 ) * id;
    b[10] = ( a[12]*s4 - a[13]*s2 + a[15]*s0) * id;
    b[11] = (-a[8]*s4  + a[9]*s2  - a[11]*s0) * id;
    b[12] = (-a[4]*c3  + a[5]*c1  - a[6]*c0 ) * id;
    b[13] = ( a[0]*c3  - a[1]*c1  + a[2]*c0 ) * id;
    b[14] = (-a[12]*s3 + a[13]*s1 - a[14]*s0) * id;
    b[15] = ( a[8]*s3  - a[9]*s1  + a[10]*s0) * id;
}

__device__ __forceinline__ void mm4(const float a[16], const float b[16], float c[16]) {
    #pragma unroll
    for (int i = 0; i < 4; i++)
        #pragma unroll
        for (int j = 0; j < 4; j++)
            c[i*4+j] = a[i*4]*b[j] + a[i*4+1]*b[4+j] + a[i*4+2]*b[8+j] + a[i*4+3]*b[12+j];
}

__device__ __forceinline__ void mm3(const float a[9], const float b[9], float c[9]) {
    #pragma unroll
    for (int i = 0; i < 3; i++)
        #pragma unroll
        for (int j = 0; j < 3; j++)
            c[i*3+j] = a[i*3]*b[j] + a[i*3+1]*b[3+j] + a[i*3+2]*b[6+j];
}

__device__ __forceinline__ float det3(const float g[9]) {
    return g[0]*(g[4]*g[8]-g[5]*g[7])
         - g[1]*(g[3]*g[8]-g[5]*g[6])
         + g[2]*(g[3]*g[7]-g[4]*g[6]);
}

__device__ __forceinline__ void inv3(const float g[9], float o[9]) {
    float c00 = g[4]*g[8] - g[5]*g[7];
    float c01 = g[5]*g[6] - g[3]*g[8];
    float c02 = g[3]*g[7] - g[4]*g[6];
    float det = g[0]*c00 + g[1]*c01 + g[2]*c02;
    float id = 1.0f / det;
    o[0] = c00 * id;
    o[1] = (g[2]*g[7] - g[1]*g[8]) * id;
    o[2] = (g[1]*g[5] - g[2]*g[4]) * id;
    o[3] = c01 * id;
    o[4] = (g[0]*g[8] - g[2]*g[6]) * id;
    o[5] = (g[2]*g[3] - g[0]*g[5]) * id;
    o[6] = c02 * id;
    o[7] = (g[1]*g[6] - g[0]*g[7]) * id;
    o[8] = (g[0]*g[4] - g[1]*g[3]) * id;
}

// ---------- kernel 1: per-pixel Mueller decomposition (fp32, R6-proven math) ----------
// Default launch bounds: 72 VGPR / no scratch. R6's A/B showed forcing 8 waves/EU
// throttles to 32 VGPR + ~580 MB scratch spill traffic -> 5x slower. Do not force.

__global__ __launch_bounds__(256) void mm_main_kernel(
    const float* __restrict__ x,
    float* __restrict__ out,
    float2* __restrict__ cs_sn)
{
    int idx = blockIdx.x * 256 + threadIdx.x;
    if (idx >= BB * HWW) return;
    int b = idx >> 18;            // HWW = 2^18
    int p = idx & (HWW - 1);
    const float* xb = x + (size_t)b * 48 * HWW + p;

    float Im[16], Am[16], Wm[16];
    #pragma unroll
    for (int k = 0; k < 16; k++) Im[k] = xb[(size_t)k * HWW];
    #pragma unroll
    for (int k = 0; k < 16; k++) Am[k] = xb[(size_t)(16 + k) * HWW];
    #pragma unroll
    for (int k = 0; k < 16; k++) Wm[k] = xb[(size_t)(32 + k) * HWW];

    float inten = 0.0f;
    #pragma unroll
    for (int k = 0; k < 16; k++) inten += Im[k];
    inten *= (1.0f / 16.0f);

    float iA[16], iW[16], T4[16], M[16];
    inv4(Am, iA);
    inv4(Wm, iW);
    mm4(iA, Im, T4);
    mm4(T4, iW, M);

    float* ob = out + (size_t)b * NCH_OUT * HWW + p;
    ob[0] = inten;
    #pragma unroll
    for (int k = 0; k < 16; k++) ob[(size_t)(1 + k) * HWW] = M[k];

    // ---- charpoly realizability mask via coherency matrix H ----
    float c00r[4], c11r[4], c01r[4], c01i[4];
    #pragma unroll
    for (int i = 0; i < 4; i++) {
        c00r[i] = M[4*i+0] + M[4*i+1];
        c11r[i] = M[4*i+0] - M[4*i+1];
        c01r[i] = M[4*i+2];
        c01i[i] = M[4*i+3];
    }
    float Hr[4][4], Hi[4][4];
    Hr[0][0] = 0.25f*(c00r[0]+c00r[1]); Hi[0][0] = 0.0f;
    Hr[0][1] = 0.25f*(c01r[0]+c01r[1]); Hi[0][1] = 0.25f*(c01i[0]+c01i[1]);
    Hr[1][0] = Hr[0][1];                Hi[1][0] = -Hi[0][1];
    Hr[1][1] = 0.25f*(c11r[0]+c11r[1]); Hi[1][1] = 0.0f;
    Hr[0][2] = 0.25f* c00r[2];               Hi[0][2] = -0.25f*c00r[3];
    Hr[0][3] = 0.25f*(c01r[2]+c01i[3]);      Hi[0][3] = 0.25f*(c01i[2]-c01r[3]);
    Hr[1][2] = 0.25f*(c01r[2]-c01i[3]);      Hi[1][2] = 0.25f*(-c01i[2]-c01r[3]);
    Hr[1][3] = 0.25f* c11r[2];               Hi[1][3] = -0.25f*c11r[3];
    Hr[2][0] = 0.25f* c00r[2];               Hi[2][0] = 0.25f*c00r[3];
    Hr[2][1] = 0.25f*(c01r[2]-c01i[3]);      Hi[2][1] = 0.25f*(c01i[2]+c01r[3]);
    Hr[3][0] = 0.25f*(c01r[2]+c01i[3]);      Hi[3][0] = 0.25f*(-c01i[2]+c01r[3]);
    Hr[3][1] = 0.25f* c11r[2];               Hi[3][1] = 0.25f*c11r[3];
    Hr[2][2] = 0.25f*(c00r[0]-c00r[1]); Hi[2][2] = 0.0f;
    Hr[2][3] = 0.25f*(c01r[0]-c01r[1]); Hi[2][3] = 0.25f*(c01i[0]-c01i[1]);
    Hr[3][2] = Hr[2][3];                Hi[3][2] = -Hi[2][3];
    Hr[3][3] = 0.25f*(c11r[0]-c11r[1]); Hi[3][3] = 0.0f;

    float p1 = Hr[0][0]+Hr[1][1]+Hr[2][2]+Hr[3][3];
    float p2 = 0.0f, p3 = 0.0f, p4 = 0.0f;
    #pragma unroll
    for (int i = 0; i < 4; i++) {
        #pragma unroll
        for (int j = 0; j < 4; j++) {
            float h2r = 0.0f, h2i = 0.0f;
            #pragma unroll
            for (int k = 0; k < 4; k++) {
                h2r += Hr[i][k]*Hr[k][j] - Hi[i][k]*Hi[k][j];
                h2i += Hr[i][k]*Hi[k][j] + Hi[i][k]*Hr[k][j];
            }
            if (i == j) p2 += h2r;
            p3 += h2r*Hr[i][j] + h2i*Hi[i][j];
            p4 += h2r*h2r + h2i*h2i;
        }
    }
    float cc1 = p1;
    float cc2 = (cc1*p1 - p2) * 0.5f;
    float cc3 = (cc2*p1 - cc1*p2 + p3) * (1.0f/3.0f);
    float cc4 = (cc3*p1 - cc2*p2 + cc1*p3 - p4) * 0.25f;
    const float tol = -1e-5f;
    bool v = (cc1 > tol) && (cc2 > tol) && (cc3 > tol) && (cc4 > tol);

    // ---- diattenuator removal ----
    float im00 = 1.0f / (M[0] + 1e-6f);
    float Mn[16];
    #pragma unroll
    for (int k = 0; k < 16; k++) Mn[k] = M[k] * im00;
    float D0 = Mn[1], D1 = Mn[2], D2 = Mn[3];
    float d = sqrtf(D0*D0 + D1*D1 + D2*D2 + 1e-12f);
    float dcl = fminf(fmaxf(d, 0.0f), 0.9999f);
    float sq = sqrtf(1.0f - dcl*dcl);
    float idn = 1.0f / (d + 1e-9f);
    float Dn0 = D0*idn, Dn1 = D1*idn, Dn2 = D2*idn;
    float osq = 1.0f - sq;
    float MD[16];
    MD[0] = 1.0f; MD[1] = D0; MD[2] = D1; MD[3] = D2;
    MD[4] = D0;  MD[8] = D1; MD[12] = D2;
    MD[5]  = sq + osq*Dn0*Dn0; MD[6]  = osq*Dn0*Dn1;      MD[7]  = osq*Dn0*Dn2;
    MD[9]  = osq*Dn1*Dn0;      MD[10] = sq + osq*Dn1*Dn1; MD[11] = osq*Dn1*Dn2;
    MD[13] = osq*Dn2*Dn0;      MD[14] = osq*Dn2*Dn1;      MD[15] = sq + osq*Dn2*Dn2;
    float iMD[16]; inv4(MD, iMD);
    float Mp[16]; mm4(Mn, iMD, Mp);
    float mp[9] = {Mp[5],Mp[6],Mp[7], Mp[9],Mp[10],Mp[11], Mp[13],Mp[14],Mp[15]};

    float G[9];
    G[0] = mp[0]*mp[0]+mp[1]*mp[1]+mp[2]*mp[2];
    G[1] = mp[0]*mp[3]+mp[1]*mp[4]+mp[2]*mp[5];
    G[2] = mp[0]*mp[6]+mp[1]*mp[7]+mp[2]*mp[8];
    G[3] = G[1];
    G[4] = mp[3]*mp[3]+mp[4]*mp[4]+mp[5]*mp[5];
    G[5] = mp[3]*mp[6]+mp[4]*mp[7]+mp[5]*mp[8];
    G[6] = G[2]; G[7] = G[5];
    G[8] = mp[6]*mp[6]+mp[7]*mp[7]+mp[8]*mp[8];

    // ---- eigvals of symmetric 3x3 (trig formula) ----
    float qq = (G[0]+G[4]+G[8]) * (1.0f/3.0f);
    float Gq[9];
    #pragma unroll
    for (int k = 0; k < 9; k++) Gq[k] = G[k];
    Gq[0] -= qq; Gq[4] -= qq; Gq[8] -= qq;
    float ssum = 0.0f;
    #pragma unroll
    for (int k = 0; k < 9; k++) ssum += Gq[k]*Gq[k];
    float pp = sqrtf(ssum * (1.0f/6.0f) + 1e-20f);
    float rr = det3(Gq) / (2.0f * pp*pp*pp);
    rr = fminf(fmaxf(rr, -1.0f + 1e-6f), 1.0f - 1e-6f);
    float phi = acosf(rr) * (1.0f/3.0f);
    float l1 = qq + 2.0f*pp*cosf(phi);
    float l3 = qq + 2.0f*pp*cosf(phi + 2.0943951023931953f);
    float l2 = 3.0f*qq - l1 - l3;

    float s1v = sqrtf(fmaxf(l1, 1e-12f));
    float s2v = sqrtf(fmaxf(l2, 1e-12f));
    float s3v = sqrtf(fmaxf(l3, 1e-12f));
    float e1 = s1v + s2v + s3v;
    float e2 = s1v*s2v + s2v*s3v + s3v*s1v;
    float e3 = s1v*s2v*s3v;
    float sgn = (det3(mp) >= 0.0f) ? 1.0f : -1.0f;

    float LHS[9], RHS[9];
    #pragma unroll
    for (int k = 0; k < 9; k++) { LHS[k] = G[k]; RHS[k] = e1*G[k]; }
    float e2p = e2 + 1e-9f;
    LHS[0] += e2p; LHS[4] += e2p; LHS[8] += e2p;
    RHS[0] += e3;  RHS[4] += e3;  RHS[8] += e3;
    float iL[9]; inv3(LHS, iL);
    float mDel[9]; mm3(iL, RHS, mDel);
    #pragma unroll
    for (int k = 0; k < 9; k++) mDel[k] *= sgn;
    float iDel[9]; inv3(mDel, iDel);
    float mR[9]; mm3(iDel, mp, mR);

    float t1 = mR[0] + mR[4];
    float t2 = mR[3] - mR[1];
    float arg = sqrtf(t1*t1 + t2*t2 + 1e-12f) - 1.0f;
    arg = fminf(fmaxf(arg, -1.0f + 1e-6f), 1.0f - 1e-6f);
    const float RAD2DEG = 57.29577951308232f;
    float linr = acosf(arg) * RAD2DEG;
    float a1 = mR[5] - mR[7];
    float a2 = mR[6] - mR[2];
    bool safe = (a1*a1 + a2*a2) > 1e-12f;
    float azi = 0.5f * RAD2DEG * atan2f(safe ? a2 : 0.0f, safe ? a1 : 1.0f);
    azi = fmodf(azi, 180.0f);
    if (azi < 0.0f) azi += 180.0f;
    float totp = 1.0f - (fabsf(mDel[0])+fabsf(mDel[4])+fabsf(mDel[8])) * (1.0f/3.0f);
    if (!v) { linr = 0.0f; totp = 0.0f; azi = 0.0f; }

    ob[(size_t)17 * HWW] = linr;
    ob[(size_t)18 * HWW] = totp;
    ob[(size_t)19 * HWW] = azi;

    if (cs_sn) {
        float ang = azi * 0.03490658503988659f; // 2 * radians(azi)
        cs_sn[idx] = make_float2(__cosf(ang), __sinf(ang)); // smooth path only: HW trig ok
    }
}

// ---------- kernel 2: LDS-tiled separable 8x8 reflect box filter -> circular std ----------

__global__ __launch_bounds__(256) void mm_std_ws(
    const float2* __restrict__ cs_sn, float* __restrict__ out)
{
    __shared__ float2 tile[23][24];  // rows y0-4..y0+18, cols x0-4..x0+18
    __shared__ float2 Hs[23][17];    // horizontal 8-sums
    int tid = threadIdx.x;
    int x0 = blockIdx.x * 16, y0 = blockIdx.y * 16, b = blockIdx.z;
    const float2* src = cs_sn + (size_t)b * HWW;

    for (int e = tid; e < 529; e += 256) {   // 23x23 halo tile
        int ty = e / 23, tx = e - ty * 23;
        int gy = y0 - 4 + ty; gy = gy < 0 ? -gy : (gy >= HH ? 2*HH - 2 - gy : gy);
        int gx = x0 - 4 + tx; gx = gx < 0 ? -gx : (gx >= WWD ? 2*WWD - 2 - gx : gx);
        tile[ty][tx] = src[gy * WWD + gx];
    }
    __syncthreads();

    for (int e = tid; e < 368; e += 256) {   // 23 rows x 16 out-cols
        int r = e >> 4, c = e & 15;
        float2 a = tile[r][c];
        float sc = a.x, ss = a.y;
        #pragma unroll
        for (int k = 1; k < 8; k++) { float2 t = tile[r][c + k]; sc += t.x; ss += t.y; }
        Hs[r][c] = make_float2(sc, ss);
    }
    __syncthreads();

    int tx = tid & 15, ty = tid >> 4;
    float2 a = Hs[ty][tx];
    float Cs = a.x, Ss = a.y;
    #pragma unroll
    for (int k = 1; k < 8; k++) { float2 t = Hs[ty + k][tx]; Cs += t.x; Ss += t.y; }
    Cs *= (1.0f/64.0f);
    Ss *= (1.0f/64.0f);
    float R = sqrtf(Cs*Cs + Ss*Ss + 1e-12f);
    R = fminf(fmaxf(R, 1e-6f), 1.0f - 1e-7f);
    float stdv = 57.29577951308232f * 0.5f * sqrtf(-2.0f * logf(R));
    out[((size_t)(b * NCH_OUT + 20)) * HWW + (size_t)(y0 + ty) * WWD + (x0 + tx)] = stdv;
}

// Fallback (ws too small): recompute cos/sin from azi output channel, naive 64-tap.
__global__ __launch_bounds__(256) void mm_std_nws(float* __restrict__ out)
{
    int x = blockIdx.x * 16 + (threadIdx.x & 15);
    int y = blockIdx.y * 16 + (threadIdx.x >> 4);
    int b = blockIdx.z;
    const float* azi_ch = out + ((size_t)(b * NCH_OUT + 19)) * HWW;
    float Cs = 0.0f, Ss = 0.0f;
    #pragma unroll
    for (int ky = 0; ky < 8; ky++) {
        int yy = y - 4 + ky;
        yy = (yy < 0) ? -yy : ((yy >= HH) ? (2*HH - 2 - yy) : yy);
        int rowoff = yy * WWD;
        #pragma unroll
        for (int kx = 0; kx < 8; kx++) {
            int xx = x - 4 + kx;
            xx = (xx < 0) ? -xx : ((xx >= WWD) ? (2*WWD - 2 - xx) : xx);
            float azi = azi_ch[rowoff + xx];
            float ang = azi * 0.03490658503988659f;
            Cs += __cosf(ang);
            Ss += __sinf(ang);
        }
    }
    Cs *= (1.0f/64.0f);
    Ss *= (1.0f/64.0f);
    float R = sqrtf(Cs*Cs + Ss*Ss + 1e-12f);
    R = fminf(fmaxf(R, 1e-6f), 1.0f - 1e-7f);
    float stdv = 57.29577951308232f * 0.5f * sqrtf(-2.0f * logf(R));
    out[((size_t)(b * NCH_OUT + 20)) * HWW + (size_t)y * WWD + x] = stdv;
}

extern "C" void kernel_launch(void* const* d_in, const int* in_sizes, int n_in,
                              void* d_out, int out_size, void* d_ws, size_t ws_size,
                              hipStream_t stream) {
    const float* x = (const float*)d_in[0];
    float* out = (float*)d_out;
    const size_t ws_needed = sizeof(float2) * (size_t)BB * HWW;  // 16 MiB
    bool ws_ok = ws_size >= ws_needed;
    float2* cs_sn = ws_ok ? (float2*)d_ws : nullptr;

    dim3 g1((BB * HWW + 255) / 256);
    mm_main_kernel<<<g1, 256, 0, stream>>>(x, out, cs_sn);

    dim3 g2(WWD / 16, HH / 16, BB);
    if (ws_ok) {
        mm_std_ws<<<g2, 256, 0, stream>>>(cs_sn, out);
    } else {
        mm_std_nws<<<g2, 256, 0, stream>>>(out);
    }
}

// Round 9
// 168.959 us; speedup vs baseline: 1.7444x; 1.0018x over previous
//
#include <hip/hip_runtime.h>
#include <math.h>

#define BB 2
#define HH 512
#define WWD 512
#define HWW (HH*WWD)
#define NCH_OUT 21

__device__ __forceinline__ float frcp(float x)  { return __builtin_amdgcn_rcpf(x); }
__device__ __forceinline__ float fsqrt(float x) { return __builtin_amdgcn_sqrtf(x); }

// ---------- small dense helpers (row-major, constant-indexed -> registers) ----------
// FAST=false: exact IEEE divide (mask-upstream paths stay bit-identical to R7).
// FAST=true : v_rcp_f32 (post-mask paths only).

template <bool FAST>
__device__ __forceinline__ void inv4(const float a[16], float b[16]) {
    float s0 = a[0]*a[5] - a[4]*a[1];
    float s1 = a[0]*a[6] - a[4]*a[2];
    float s2 = a[0]*a[7] - a[4]*a[3];
    float s3 = a[1]*a[6] - a[5]*a[2];
    float s4 = a[1]*a[7] - a[5]*a[3];
    float s5 = a[2]*a[7] - a[6]*a[3];
    float c5 = a[10]*a[15] - a[14]*a[11];
    float c4 = a[9]*a[15]  - a[13]*a[11];
    float c3 = a[9]*a[14]  - a[13]*a[10];
    float c2 = a[8]*a[15]  - a[12]*a[11];
    float c1 = a[8]*a[14]  - a[12]*a[10];
    float c0 = a[8]*a[13]  - a[12]*a[9];
    float det = s0*c5 - s1*c4 + s2*c3 + s3*c2 - s4*c1 + s5*c0;
    float id = FAST ? frcp(det) : (1.0f / det);
    b[0]  = ( a[5]*c5  - a[6]*c4  + a[7]*c3 ) * id;
    b[1]  = (-a[1]*c5  + a[2]*c4  - a[3]*c3 ) * id;
    b[2]  = ( a[13]*s5 - a[14]*s4 + a[15]*s3) * id;
    b[3]  = (-a[9]*s5  + a[10]*s4 - a[11]*s3) * id;
    b[4]  = (-a[4]*c5  + a[6]*c2  - a[7]*c1 ) * id;
    b[5]  = ( a[0]*c5  - a[2]*c2  + a[3]*c1 ) * id;
    b[6]  = (-a[12]*s5 + a[14]*s2 - a[15]*s1) * id;
    b[7]  = ( a[8]*s5  - a[10]*s2 + a[11]*s1) * id;
    b[8]  = ( a[4]*c4  - a[5]*c2  + a[7]*c0 ) * id;
    b[9]  = (-a[0]*c4  + a[1]*c2  - a[3]*c0 ) * id;
    b[10] = ( a[12]*s4 - a[13]*s2 + a[15]*s0) * id;
    b[11] = (-a[8]*s4  + a[9]*s2  - a[11]*s0) * id;
    b[12] = (-a[4]*c3  + a[5]*c1  - a[6]*c0 ) * id;
    b[13] = ( a[0]*c3  - a[1]*c1  + a[2]*c0 ) * id;
    b[14] = (-a[12]*s3 + a[13]*s1 - a[14]*s0) * id;
    b[15] = ( a[8]*s3  - a[9]*s1  + a[10]*s0) * id;
}

__device__ __forceinline__ void mm4(const float a[16], const float b[16], float c[16]) {
    #pragma unroll
    for (int i = 0; i < 4; i++)
        #pragma unroll
        for (int j = 0; j < 4; j++)
            c[i*4+j] = a[i*4]*b[j] + a[i*4+1]*b[4+j] + a[i*4+2]*b[8+j] + a[i*4+3]*b[12+j];
}

__device__ __forceinline__ void mm3(const float a[9], const float b[9], float c[9]) {
    #pragma unroll
    for (int i = 0; i < 3; i++)
        #pragma unroll
        for (int j = 0; j < 3; j++)
            c[i*3+j] = a[i*3]*b[j] + a[i*3+1]*b[3+j] + a[i*3+2]*b[6+j];
}

__device__ __forceinline__ float det3(const float g[9]) {
    return g[0]*(g[4]*g[8]-g[5]*g[7])
         - g[1]*(g[3]*g[8]-g[5]*g[6])
         + g[2]*(g[3]*g[7]-g[4]*g[6]);
}

__device__ __forceinline__ void inv3(const float g[9], float o[9]) {  // post-mask only
    float c00 = g[4]*g[8] - g[5]*g[7];
    float c01 = g[5]*g[6] - g[3]*g[8];
    float c02 = g[3]*g[7] - g[4]*g[6];
    float det = g[0]*c00 + g[1]*c01 + g[2]*c02;
    float id = frcp(det);
    o[0] = c00 * id;
    o[1] = (g[2]*g[7] - g[1]*g[8]) * id;
    o[2] = (g[1]*g[5] - g[2]*g[4]) * id;
    o[3] = c01 * id;
    o[4] = (g[0]*g[8] - g[2]*g[6]) * id;
    o[5] = (g[2]*g[3] - g[0]*g[5]) * id;
    o[6] = c02 * id;
    o[7] = (g[1]*g[6] - g[0]*g[7]) * id;
    o[8] = (g[0]*g[4] - g[1]*g[3]) * id;
}

// ---------- kernel 1: per-pixel Mueller decomposition ----------
// Default launch bounds: 72 VGPR / no scratch. R6 A/B: forcing 8 waves/EU -> 32 VGPR
// + ~580 MB spill traffic -> 5x slower. Do not force occupancy.
// R8 lesson: the charpoly accumulation ORDER below is load-bearing. The cc_i > -1e-5
// mask boundary has pixels within a reassociation-ulp; R8's upper-triangle rewrite
// flipped one (absmax 56.75). Keep this loop byte-identical to the R7-passing form.

__global__ __launch_bounds__(256) void mm_main_kernel(
    const float* __restrict__ x,
    float* __restrict__ out,
    float2* __restrict__ cs_sn)
{
    int idx = blockIdx.x * 256 + threadIdx.x;
    if (idx >= BB * HWW) return;
    int b = idx >> 18;            // HWW = 2^18
    int p = idx & (HWW - 1);
    const float* xb = x + (size_t)b * 48 * HWW + p;

    float Im[16], Am[16], Wm[16];
    #pragma unroll
    for (int k = 0; k < 16; k++) Im[k] = xb[(size_t)k * HWW];
    #pragma unroll
    for (int k = 0; k < 16; k++) Am[k] = xb[(size_t)(16 + k) * HWW];
    #pragma unroll
    for (int k = 0; k < 16; k++) Wm[k] = xb[(size_t)(32 + k) * HWW];

    float inten = 0.0f;
    #pragma unroll
    for (int k = 0; k < 16; k++) inten += Im[k];
    inten *= (1.0f / 16.0f);

    float iA[16], iW[16], T4[16], M[16];
    inv4<false>(Am, iA);          // exact: feeds M (output + mask)
    inv4<false>(Wm, iW);
    mm4(iA, Im, T4);
    mm4(T4, iW, M);

    float* ob = out + (size_t)b * NCH_OUT * HWW + p;
    ob[0] = inten;
    #pragma unroll
    for (int k = 0; k < 16; k++) ob[(size_t)(1 + k) * HWW] = M[k];

    // ---- charpoly realizability mask via coherency matrix H (R7-exact path) ----
    float c00r[4], c11r[4], c01r[4], c01i[4];
    #pragma unroll
    for (int i = 0; i < 4; i++) {
        c00r[i] = M[4*i+0] + M[4*i+1];
        c11r[i] = M[4*i+0] - M[4*i+1];
        c01r[i] = M[4*i+2];
        c01i[i] = M[4*i+3];
    }
    float Hr[4][4], Hi[4][4];
    Hr[0][0] = 0.25f*(c00r[0]+c00r[1]); Hi[0][0] = 0.0f;
    Hr[0][1] = 0.25f*(c01r[0]+c01r[1]); Hi[0][1] = 0.25f*(c01i[0]+c01i[1]);
    Hr[1][0] = Hr[0][1];                Hi[1][0] = -Hi[0][1];
    Hr[1][1] = 0.25f*(c11r[0]+c11r[1]); Hi[1][1] = 0.0f;
    Hr[0][2] = 0.25f* c00r[2];               Hi[0][2] = -0.25f*c00r[3];
    Hr[0][3] = 0.25f*(c01r[2]+c01i[3]);      Hi[0][3] = 0.25f*(c01i[2]-c01r[3]);
    Hr[1][2] = 0.25f*(c01r[2]-c01i[3]);      Hi[1][2] = 0.25f*(-c01i[2]-c01r[3]);
    Hr[1][3] = 0.25f* c11r[2];               Hi[1][3] = -0.25f*c11r[3];
    Hr[2][0] = 0.25f* c00r[2];               Hi[2][0] = 0.25f*c00r[3];
    Hr[2][1] = 0.25f*(c01r[2]-c01i[3]);      Hi[2][1] = 0.25f*(c01i[2]+c01r[3]);
    Hr[3][0] = 0.25f*(c01r[2]+c01i[3]);      Hi[3][0] = 0.25f*(-c01i[2]+c01r[3]);
    Hr[3][1] = 0.25f* c11r[2];               Hi[3][1] = 0.25f*c11r[3];
    Hr[2][2] = 0.25f*(c00r[0]-c00r[1]); Hi[2][2] = 0.0f;
    Hr[2][3] = 0.25f*(c01r[0]-c01r[1]); Hi[2][3] = 0.25f*(c01i[0]-c01i[1]);
    Hr[3][2] = Hr[2][3];                Hi[3][2] = -Hi[2][3];
    Hr[3][3] = 0.25f*(c11r[0]-c11r[1]); Hi[3][3] = 0.0f;

    float p1 = Hr[0][0]+Hr[1][1]+Hr[2][2]+Hr[3][3];
    float p2 = 0.0f, p3 = 0.0f, p4 = 0.0f;
    #pragma unroll
    for (int i = 0; i < 4; i++) {
        #pragma unroll
        for (int j = 0; j < 4; j++) {
            float h2r = 0.0f, h2i = 0.0f;
            #pragma unroll
            for (int k = 0; k < 4; k++) {
                h2r += Hr[i][k]*Hr[k][j] - Hi[i][k]*Hi[k][j];
                h2i += Hr[i][k]*Hi[k][j] + Hi[i][k]*Hr[k][j];
            }
            if (i == j) p2 += h2r;
            p3 += h2r*Hr[i][j] + h2i*Hi[i][j];
            p4 += h2r*h2r + h2i*h2i;
        }
    }
    float cc1 = p1;
    float cc2 = (cc1*p1 - p2) * 0.5f;
    float cc3 = (cc2*p1 - cc1*p2 + p3) * (1.0f/3.0f);
    float cc4 = (cc3*p1 - cc2*p2 + cc1*p3 - p4) * 0.25f;
    const float tol = -1e-5f;
    bool v = (cc1 > tol) && (cc2 > tol) && (cc3 > tol) && (cc4 > tol);

    // ---- diattenuator removal (post-mask: fast ops allowed) ----
    float im00 = frcp(M[0] + 1e-6f);
    float Mn[16];
    #pragma unroll
    for (int k = 0; k < 16; k++) Mn[k] = M[k] * im00;
    float D0 = Mn[1], D1 = Mn[2], D2 = Mn[3];
    float d = fsqrt(D0*D0 + D1*D1 + D2*D2 + 1e-12f);
    float dcl = fminf(fmaxf(d, 0.0f), 0.9999f);
    float sq = fsqrt(1.0f - dcl*dcl);
    float idn = frcp(d + 1e-9f);
    float Dn0 = D0*idn, Dn1 = D1*idn, Dn2 = D2*idn;
    float osq = 1.0f - sq;
    float MD[16];
    MD[0] = 1.0f; MD[1] = D0; MD[2] = D1; MD[3] = D2;
    MD[4] = D0;  MD[8] = D1; MD[12] = D2;
    MD[5]  = sq + osq*Dn0*Dn0; MD[6]  = osq*Dn0*Dn1;      MD[7]  = osq*Dn0*Dn2;
    MD[9]  = osq*Dn1*Dn0;      MD[10] = sq + osq*Dn1*Dn1; MD[11] = osq*Dn1*Dn2;
    MD[13] = osq*Dn2*Dn0;      MD[14] = osq*Dn2*Dn1;      MD[15] = sq + osq*Dn2*Dn2;
    float iMD[16]; inv4<true>(MD, iMD);
    float Mp[16]; mm4(Mn, iMD, Mp);
    float mp[9] = {Mp[5],Mp[6],Mp[7], Mp[9],Mp[10],Mp[11], Mp[13],Mp[14],Mp[15]};

    float G[9];
    G[0] = mp[0]*mp[0]+mp[1]*mp[1]+mp[2]*mp[2];
    G[1] = mp[0]*mp[3]+mp[1]*mp[4]+mp[2]*mp[5];
    G[2] = mp[0]*mp[6]+mp[1]*mp[7]+mp[2]*mp[8];
    G[3] = G[1];
    G[4] = mp[3]*mp[3]+mp[4]*mp[4]+mp[5]*mp[5];
    G[5] = mp[3]*mp[6]+mp[4]*mp[7]+mp[5]*mp[8];
    G[6] = G[2]; G[7] = G[5];
    G[8] = mp[6]*mp[6]+mp[7]*mp[7]+mp[8]*mp[8];

    // ---- eigvals of symmetric 3x3 (trig formula) ----
    float qq = (G[0]+G[4]+G[8]) * (1.0f/3.0f);
    float Gq[9];
    #pragma unroll
    for (int k = 0; k < 9; k++) Gq[k] = G[k];
    Gq[0] -= qq; Gq[4] -= qq; Gq[8] -= qq;
    float ssum = 0.0f;
    #pragma unroll
    for (int k = 0; k < 9; k++) ssum += Gq[k]*Gq[k];
    float pp = fsqrt(ssum * (1.0f/6.0f) + 1e-20f);
    float rr = det3(Gq) * 0.5f * frcp(pp*pp*pp);
    rr = fminf(fmaxf(rr, -1.0f + 1e-6f), 1.0f - 1e-6f);
    float phi = acosf(rr) * (1.0f/3.0f);
    float l1 = qq + 2.0f*pp*__cosf(phi);
    float l3 = qq + 2.0f*pp*__cosf(phi + 2.0943951023931953f);
    float l2 = 3.0f*qq - l1 - l3;

    float s1v = fsqrt(fmaxf(l1, 1e-12f));
    float s2v = fsqrt(fmaxf(l2, 1e-12f));
    float s3v = fsqrt(fmaxf(l3, 1e-12f));
    float e1 = s1v + s2v + s3v;
    float e2 = s1v*s2v + s2v*s3v + s3v*s1v;
    float e3 = s1v*s2v*s3v;
    float sgn = (det3(mp) >= 0.0f) ? 1.0f : -1.0f;

    float LHS[9], RHS[9];
    #pragma unroll
    for (int k = 0; k < 9; k++) { LHS[k] = G[k]; RHS[k] = e1*G[k]; }
    float e2p = e2 + 1e-9f;
    LHS[0] += e2p; LHS[4] += e2p; LHS[8] += e2p;
    RHS[0] += e3;  RHS[4] += e3;  RHS[8] += e3;
    float iL[9]; inv3(LHS, iL);
    float mDel[9]; mm3(iL, RHS, mDel);
    #pragma unroll
    for (int k = 0; k < 9; k++) mDel[k] *= sgn;
    float iDel[9]; inv3(mDel, iDel);
    float mR[9]; mm3(iDel, mp, mR);

    float t1 = mR[0] + mR[4];
    float t2 = mR[3] - mR[1];
    float arg = fsqrt(t1*t1 + t2*t2 + 1e-12f) - 1.0f;
    arg = fminf(fmaxf(arg, -1.0f + 1e-6f), 1.0f - 1e-6f);
    const float RAD2DEG = 57.29577951308232f;
    float linr = acosf(arg) * RAD2DEG;
    float a1 = mR[5] - mR[7];
    float a2 = mR[6] - mR[2];
    bool safe = (a1*a1 + a2*a2) > 1e-12f;
    float azi = 0.5f * RAD2DEG * atan2f(safe ? a2 : 0.0f, safe ? a1 : 1.0f);
    if (azi < 0.0f) azi += 180.0f;   // azi in (-90,90]: fmod(.,180) is identity, wrap exact
    float totp = 1.0f - (fabsf(mDel[0])+fabsf(mDel[4])+fabsf(mDel[8])) * (1.0f/3.0f);
    if (!v) { linr = 0.0f; totp = 0.0f; azi = 0.0f; }

    ob[(size_t)17 * HWW] = linr;
    ob[(size_t)18 * HWW] = totp;
    ob[(size_t)19 * HWW] = azi;

    if (cs_sn) {
        float ang = azi * 0.03490658503988659f; // 2 * radians(azi)
        cs_sn[idx] = make_float2(__cosf(ang), __sinf(ang));
    }
}

// ---------- kernel 2: LDS-tiled separable 8x8 reflect box filter -> circular std ----------

__global__ __launch_bounds__(256) void mm_std_ws(
    const float2* __restrict__ cs_sn, float* __restrict__ out)
{
    __shared__ float2 tile[23][24];
    __shared__ float2 Hs[23][17];
    int tid = threadIdx.x;
    int x0 = blockIdx.x * 16, y0 = blockIdx.y * 16, b = blockIdx.z;
    const float2* src = cs_sn + (size_t)b * HWW;

    for (int e = tid; e < 529; e += 256) {   // 23x23 halo tile
        int ty = e / 23, tx = e - ty * 23;
        int gy = y0 - 4 + ty; gy = gy < 0 ? -gy : (gy >= HH ? 2*HH - 2 - gy : gy);
        int gx = x0 - 4 + tx; gx = gx < 0 ? -gx : (gx >= WWD ? 2*WWD - 2 - gx : gx);
        tile[ty][tx] = src[gy * WWD + gx];
    }
    __syncthreads();

    for (int e = tid; e < 368; e += 256) {   // 23 rows x 16 out-cols
        int r = e >> 4, c = e & 15;
        float2 a = tile[r][c];
        float sc = a.x, ss = a.y;
        #pragma unroll
        for (int k = 1; k < 8; k++) { float2 t = tile[r][c + k]; sc += t.x; ss += t.y; }
        Hs[r][c] = make_float2(sc, ss);
    }
    __syncthreads();

    int tx = tid & 15, ty = tid >> 4;
    float2 a = Hs[ty][tx];
    float Cs = a.x, Ss = a.y;
    #pragma unroll
    for (int k = 1; k < 8; k++) { float2 t = Hs[ty + k][tx]; Cs += t.x; Ss += t.y; }
    Cs *= (1.0f/64.0f);
    Ss *= (1.0f/64.0f);
    float R = fsqrt(Cs*Cs + Ss*Ss + 1e-12f);
    R = fminf(fmaxf(R, 1e-6f), 1.0f - 1e-7f);
    float stdv = 57.29577951308232f * 0.5f * fsqrt(-2.0f * __logf(R));
    out[((size_t)(b * NCH_OUT + 20)) * HWW + (size_t)(y0 + ty) * WWD + (x0 + tx)] = stdv;
}

// Fallback (ws too small): recompute cos/sin from azi output channel, naive 64-tap.
__global__ __launch_bounds__(256) void mm_std_nws(float* __restrict__ out)
{
    int x = blockIdx.x * 16 + (threadIdx.x & 15);
    int y = blockIdx.y * 16 + (threadIdx.x >> 4);
    int b = blockIdx.z;
    const float* azi_ch = out + ((size_t)(b * NCH_OUT + 19)) * HWW;
    float Cs = 0.0f, Ss = 0.0f;
    #pragma unroll
    for (int ky = 0; ky < 8; ky++) {
        int yy = y - 4 + ky;
        yy = (yy < 0) ? -yy : ((yy >= HH) ? (2*HH - 2 - yy) : yy);
        int rowoff = yy * WWD;
        #pragma unroll
        for (int kx = 0; kx < 8; kx++) {
            int xx = x - 4 + kx;
            xx = (xx < 0) ? -xx : ((xx >= WWD) ? (2*WWD - 2 - xx) : xx);
            float azi = azi_ch[rowoff + xx];
            float ang = azi * 0.03490658503988659f;
            Cs += __cosf(ang);
            Ss += __sinf(ang);
        }
    }
    Cs *= (1.0f/64.0f);
    Ss *= (1.0f/64.0f);
    float R = fsqrt(Cs*Cs + Ss*Ss + 1e-12f);
    R = fminf(fmaxf(R, 1e-6f), 1.0f - 1e-7f);
    float stdv = 57.29577951308232f * 0.5f * fsqrt(-2.0f * __logf(R));
    out[((size_t)(b * NCH_OUT + 20)) * HWW + (size_t)y * WWD + x] = stdv;
}

extern "C" void kernel_launch(void* const* d_in, const int* in_sizes, int n_in,
                              void* d_out, int out_size, void* d_ws, size_t ws_size,
                              hipStream_t stream) {
    const float* x = (const float*)d_in[0];
    float* out = (float*)d_out;
    const size_t ws_needed = sizeof(float2) * (size_t)BB * HWW;  // 16 MiB
    bool ws_ok = ws_size >= ws_needed;
    float2* cs_sn = ws_ok ? (float2*)d_ws : nullptr;

    dim3 g1((BB * HWW + 255) / 256);
    mm_main_kernel<<<g1, 256, 0, stream>>>(x, out, cs_sn);

    dim3 g2(WWD / 16, HH / 16, BB);
    if (ws_ok) {
        mm_std_ws<<<g2, 256, 0, stream>>>(cs_sn, out);
    } else {
        mm_std_nws<<<g2, 256, 0, stream>>>(out);
    }
}